// Round 11
// baseline (292.188 us; speedup 1.0000x reference)
//
#include <hip/hip_runtime.h>

#define BN_EPS 1e-5f

typedef short s8v __attribute__((ext_vector_type(8)));
typedef float f4v __attribute__((ext_vector_type(4)));
typedef unsigned short u4v __attribute__((ext_vector_type(4)));
typedef unsigned int u2v __attribute__((ext_vector_type(2)));

__device__ __forceinline__ unsigned short f2bf(float f) {
  union { float f; unsigned u; } v; v.f = f;
  unsigned r = v.u + 0x7FFF + ((v.u >> 16) & 1);
  return (unsigned short)(r >> 16);
}
__device__ __forceinline__ float bf2f(unsigned short u) {
  union { unsigned u; float f; } v; v.u = ((unsigned)u) << 16; return v.f;
}

#define CHUNK 4096
#define NBMAX 512

// --------- fused prep: bucket histogram (blocks [0,histB)) + xcast + 6 W transposes
// R8: per-bucket LDS histogram + aggregated atomics (77k vs 800k scattered).
__global__ __launch_bounds__(256) void prep_kernel(
    const int* __restrict__ dst, int* __restrict__ bucket_cnt, int E, int histB,
    const float* __restrict__ x, unsigned short* __restrict__ xb,
    const float* __restrict__ Wl1, const float* __restrict__ Wr1,
    const float* __restrict__ Wl2, const float* __restrict__ Wr2,
    const float* __restrict__ W1, const float* __restrict__ W2,
    unsigned short* __restrict__ Wl1t, unsigned short* __restrict__ Wr1t,
    unsigned short* __restrict__ Wl2t, unsigned short* __restrict__ Wr2t,
    unsigned short* __restrict__ W1t, unsigned short* __restrict__ W2t,
    int N, int xblocks) {
  __shared__ int h[NBMAX];
  int blk = blockIdx.x;
  int t = threadIdx.x;
  if (blk < histB) {
    for (int i = t; i < NBMAX; i += 256) h[i] = 0;
    __syncthreads();
    int base = blk * CHUNK;
    int cnt = min(CHUNK, E - base);
    for (int i = t; i < cnt; i += 256) atomicAdd(&h[dst[base + i] >> 7], 1);
    __syncthreads();
    for (int i = t; i < NBMAX; i += 256)
      if (h[i] > 0) atomicAdd(&bucket_cnt[i], h[i]);
    return;
  }
  blk -= histB;
  if (blk < xblocks) {
    int tt = blk * 256 + t;
    if (tt < N * 128) {
      int col = tt & 127;
      int n = tt >> 7;
      xb[tt] = (col < 100) ? f2bf(x[n * 100 + col]) : (unsigned short)0;
    }
    return;
  }
  int w = blk - xblocks;
  const float* W; unsigned short* Wt; int K, C, base;
  if (w < 64)       { W = Wl1; Wt = Wl1t; K = 100; C = 128; base = 0;   }
  else if (w < 128) { W = Wr1; Wt = Wr1t; K = 100; C = 128; base = 64;  }
  else if (w < 192) { W = Wl2; Wt = Wl2t; K = 128; C = 128; base = 128; }
  else if (w < 256) { W = Wr2; Wt = Wr2t; K = 128; C = 128; base = 192; }
  else if (w < 320) { W = W1;  Wt = W1t;  K = 128; C = 128; base = 256; }
  else              { W = W2;  Wt = W2t;  K = 128; C = 64;  base = 320; }
  int tt = (w - base) * 256 + t;
  if (tt >= C * 128) return;
  int c = tt >> 7;
  int k = tt & 127;
  Wt[tt] = (k < K) ? f2bf(W[k * C + c]) : (unsigned short)0;
}

// ------- single 512-wide scan of bucket counts
__global__ __launch_bounds__(512) void bucket_scan_kernel(
    const int* __restrict__ bucket_cnt, int* __restrict__ bucket_start,
    int* __restrict__ gcursor) {
  __shared__ int sh[512];
  int t = threadIdx.x;
  sh[t] = bucket_cnt[t];
  __syncthreads();
  for (int d = 1; d < 512; d <<= 1) {
    int v = (t >= d) ? sh[t - d] : 0;
    __syncthreads();
    sh[t] += v;
    __syncthreads();
  }
  int excl = (t == 0) ? 0 : sh[t - 1];
  bucket_start[t] = excl;
  gcursor[t] = excl;
  if (t == 511) bucket_start[512] = sh[511];   // == E
}

// ------------------- CSR phase A: LDS-staged bucket scatter (kills partial-line writes)
__global__ __launch_bounds__(256) void csr_bucket_kernel(
    const int* __restrict__ src, const int* __restrict__ dst,
    int* __restrict__ gcursor, unsigned* __restrict__ pairs, int E) {
  __shared__ int h[NBMAX];
  __shared__ int off[NBMAX];
  __shared__ int cnt2[NBMAX];
  __shared__ int gadj[NBMAX];
  __shared__ unsigned pbuf[CHUNK];
  __shared__ unsigned short bidx[CHUNK];
  int t = threadIdx.x;
  int base = blockIdx.x * CHUNK;
  int cnt = min(CHUNK, E - base);
  for (int i = t; i < NBMAX; i += 256) { h[i] = 0; cnt2[i] = 0; }
  __syncthreads();
  for (int i = t; i < cnt; i += 256) atomicAdd(&h[dst[base + i] >> 7], 1);
  __syncthreads();
  off[t] = h[t]; off[t + 256] = h[t + 256];
  __syncthreads();
  for (int d = 1; d < 512; d <<= 1) {
    int v0 = (t >= d) ? off[t - d] : 0;
    int v1 = off[t + 256 - d];
    __syncthreads();
    off[t] += v0; off[t + 256] += v1;
    __syncthreads();
  }
  int e0 = off[t] - h[t];
  int e1 = off[t + 256] - h[t + 256];
  __syncthreads();
  off[t] = e0; off[t + 256] = e1;
  __syncthreads();
  for (int i = t; i < NBMAX; i += 256) {
    int c = h[i];
    if (c > 0) gadj[i] = atomicAdd(&gcursor[i], c) - off[i];
  }
  __syncthreads();
  for (int i = t; i < cnt; i += 256) {
    int s = src[base + i];
    int d = dst[base + i];
    int b = d >> 7;
    int p = off[b] + atomicAdd(&cnt2[b], 1);
    pbuf[p] = (unsigned)s | ((unsigned)d << 16);   // both < 2^16 (N=50000)
    bidx[p] = (unsigned short)b;
  }
  __syncthreads();
  for (int i = t; i < cnt; i += 256)
    pairs[gadj[bidx[i]] + i] = pbuf[i];
}

// ------- CSR phase B + deg: one block per bucket. Pass 1 counts the bucket's 128
// node degrees in LDS -> 128-wide scan -> row_start/deg coalesced stores.
// Pass 2 scatters eidx (pairs L2-hot).
__global__ __launch_bounds__(256) void csr_fill_deg_kernel(
    const unsigned* __restrict__ pairs, const int* __restrict__ bucket_start,
    int* __restrict__ eidx, int* __restrict__ row_start, int* __restrict__ deg,
    int N) {
  __shared__ int cnt[128];
  __shared__ int scn[128];
  __shared__ int cur[128];
  int b = blockIdx.x;
  int node0 = b << 7;
  int t = threadIdx.x;
  int pbeg = bucket_start[b];
  int pend = bucket_start[b + 1];
  if (t < 128) cnt[t] = 0;
  __syncthreads();
  for (int i = pbeg + t; i < pend; i += 256)
    atomicAdd(&cnt[(int)(pairs[i] >> 16) - node0], 1);
  __syncthreads();
  if (t < 128) scn[t] = cnt[t];
  __syncthreads();
  for (int d = 1; d < 128; d <<= 1) {
    int v = (t < 128 && t >= d) ? scn[t - d] : 0;
    __syncthreads();
    if (t < 128) scn[t] += v;
    __syncthreads();
  }
  if (t < 128) {
    int node = node0 + t;
    if (node < N) {
      int rs = pbeg + scn[t] - cnt[t];    // exclusive in-bucket prefix
      row_start[node] = rs;
      deg[node] = cnt[t];
      cur[t] = rs;
    }
  }
  __syncthreads();
  for (int i = pbeg + t; i < pend; i += 256) {
    unsigned p = pairs[i];
    int pos = atomicAdd(&cur[(int)(p >> 16) - node0], 1);
    eidx[pos] = (int)(p & 0xFFFFu);
  }
}

// ------------------ gather mean over bf16 rows (1 wave / node), R9 pair-load
// (known-good, 291us total). R10's cooperative tiled gather FAILED: cooperative
// launch is dropped inside the harness's graph capture (gather never ran,
// absmax 2.85 == downstream of poison means). L2-tiling w/ register accumulators
// is unreachable here; gathers stay at the random-read floor (R9 A/B: BW-bound,
// not issue-bound).
__global__ __launch_bounds__(256) void gather_kernel(
    const unsigned short* __restrict__ feat, const int* __restrict__ eidx,
    const int* __restrict__ row_start, const int* __restrict__ deg,
    unsigned short* __restrict__ mean_out, int N) {
  int wave = threadIdx.x >> 6;
  int lane = threadIdx.x & 63;
  int node = blockIdx.x * 4 + wave;
  if (node >= N) return;
  int beg = row_start[node];
  int d = deg[node];
  int l2 = lane & 31;
  int half = lane >> 5;
  float a0 = 0.0f, a1 = 0.0f, a2 = 0.0f, a3 = 0.0f;
  for (int i0 = 0; i0 < d; i0 += 64) {
    int cnt = min(64, d - i0);
    int my = (lane < cnt) ? eidx[beg + i0 + lane] : 0;
    int j = 0;
    for (; j + 15 < cnt; j += 16) {
      // 8 pair-loads = 16 rows in flight
      int s0 = __shfl(my, j + 0 + half);
      int s1 = __shfl(my, j + 2 + half);
      int s2 = __shfl(my, j + 4 + half);
      int s3 = __shfl(my, j + 6 + half);
      int s4 = __shfl(my, j + 8 + half);
      int s5 = __shfl(my, j + 10 + half);
      int s6 = __shfl(my, j + 12 + half);
      int s7 = __shfl(my, j + 14 + half);
      u2v v0 = *(const u2v*)(feat + (size_t)s0 * 128 + l2 * 4);
      u2v v1 = *(const u2v*)(feat + (size_t)s1 * 128 + l2 * 4);
      u2v v2 = *(const u2v*)(feat + (size_t)s2 * 128 + l2 * 4);
      u2v v3 = *(const u2v*)(feat + (size_t)s3 * 128 + l2 * 4);
      u2v v4 = *(const u2v*)(feat + (size_t)s4 * 128 + l2 * 4);
      u2v v5 = *(const u2v*)(feat + (size_t)s5 * 128 + l2 * 4);
      u2v v6 = *(const u2v*)(feat + (size_t)s6 * 128 + l2 * 4);
      u2v v7 = *(const u2v*)(feat + (size_t)s7 * 128 + l2 * 4);
      a0 += bf2f((unsigned short)v0[0]) + bf2f((unsigned short)v1[0])
          + bf2f((unsigned short)v2[0]) + bf2f((unsigned short)v3[0])
          + bf2f((unsigned short)v4[0]) + bf2f((unsigned short)v5[0])
          + bf2f((unsigned short)v6[0]) + bf2f((unsigned short)v7[0]);
      a1 += bf2f((unsigned short)(v0[0] >> 16)) + bf2f((unsigned short)(v1[0] >> 16))
          + bf2f((unsigned short)(v2[0] >> 16)) + bf2f((unsigned short)(v3[0] >> 16))
          + bf2f((unsigned short)(v4[0] >> 16)) + bf2f((unsigned short)(v5[0] >> 16))
          + bf2f((unsigned short)(v6[0] >> 16)) + bf2f((unsigned short)(v7[0] >> 16));
      a2 += bf2f((unsigned short)v0[1]) + bf2f((unsigned short)v1[1])
          + bf2f((unsigned short)v2[1]) + bf2f((unsigned short)v3[1])
          + bf2f((unsigned short)v4[1]) + bf2f((unsigned short)v5[1])
          + bf2f((unsigned short)v6[1]) + bf2f((unsigned short)v7[1]);
      a3 += bf2f((unsigned short)(v0[1] >> 16)) + bf2f((unsigned short)(v1[1] >> 16))
          + bf2f((unsigned short)(v2[1] >> 16)) + bf2f((unsigned short)(v3[1] >> 16))
          + bf2f((unsigned short)(v4[1] >> 16)) + bf2f((unsigned short)(v5[1] >> 16))
          + bf2f((unsigned short)(v6[1] >> 16)) + bf2f((unsigned short)(v7[1] >> 16));
    }
    for (; j < cnt; j += 2) {
      int jj = j + half;
      bool act = jj < cnt;
      int s = __shfl(my, act ? jj : 0);     // per-lane index (ds_bpermute)
      u2v v = *(const u2v*)(feat + (size_t)s * 128 + l2 * 4);
      if (act) {
        a0 += bf2f((unsigned short)v[0]);
        a1 += bf2f((unsigned short)(v[0] >> 16));
        a2 += bf2f((unsigned short)v[1]);
        a3 += bf2f((unsigned short)(v[1] >> 16));
      }
    }
  }
  // cross-half reduce: lane L and L^32 hold the same 4 columns for different rows
  a0 += __shfl_xor(a0, 32);
  a1 += __shfl_xor(a1, 32);
  a2 += __shfl_xor(a2, 32);
  a3 += __shfl_xor(a3, 32);
  float inv = 1.0f / fmaxf((float)d, 1.0f);
  if (lane < 32) {
    u2v o;
    o[0] = (unsigned)f2bf(a0 * inv) | ((unsigned)f2bf(a1 * inv) << 16);
    o[1] = (unsigned)f2bf(a2 * inv) | ((unsigned)f2bf(a3 * inv) << 16);
    ((u2v*)(mean_out + (size_t)node * 128))[l2] = o;
  }
}

// --------------------------------------------------------- MFMA GEMM (K padded to 128)
// R10 structure (32-row blocks, LDS-staged swizzled A, all-K register B).
// BNIN folds the 8 stat slots -> scale/shift in-kernel (no bn_prep launch).
template<int COLS, bool DUAL, bool RELU, bool F32OUT, bool BF16OUT, bool STATS, bool BNIN>
__global__ __launch_bounds__(256, DUAL ? 4 : 5) void mfma_gemm_kernel(
    const unsigned short* __restrict__ A1, const unsigned short* __restrict__ W1t,
    const unsigned short* __restrict__ A2, const unsigned short* __restrict__ W2t,
    const float* __restrict__ bias,
    const float* __restrict__ bsum, const float* __restrict__ bsq,
    const float* __restrict__ bg, const float* __restrict__ bbe,
    float* __restrict__ outF, unsigned short* __restrict__ outB,
    float* __restrict__ sum, float* __restrict__ sq, int N) {
  constexpr int CTW = COLS / 64;             // col-tiles per wave (128->2, 64->1)
  constexpr int CH = COLS / 4;               // f4 chunks per row
  constexpr int RS = COLS + 4;
  constexpr int NA = DUAL ? 2 : 1;
  constexpr int OUT_OFF = 8192 * NA;
  constexpr int BNL_OFF = OUT_OFF + 32 * RS * 4;
  constexpr int SMEM_SZ = BNL_OFF + (BNIN ? 1024 : 0);
  __shared__ char smem[SMEM_SZ];
  float* outl = (float*)(smem + OUT_OFF);
  float* reds = (float*)smem;                // alias A-stage (dead before stats write)
  float* redq = (float*)(smem + 4096);
  float* bnl  = (float*)(smem + BNL_OFF);
  int t = threadIdx.x;
  int wave = t >> 6;
  int lane = t & 63;
  int quad = lane >> 4;
  int m = lane & 15;
  int blk = blockIdx.x * 32;
  int col0 = wave * (16 * CTW);

  // ---- BNIN: fold stats -> scale/shift (covered by the stage barrier below)
  if (BNIN && t < 128) {
    float S = 0.0f, SS = 0.0f;
#pragma unroll
    for (int k = 0; k < 8; ++k) { S += bsum[k * 128 + t]; SS += bsq[k * 128 + t]; }
    float invN = 1.0f / (float)N;
    float mn = S * invN;
    float var = SS * invN - mn * mn;
    float sc = bg[t] * rsqrtf(var + BN_EPS);
    bnl[2 * t] = sc;
    bnl[2 * t + 1] = bbe[t] - mn * sc;
  }

  // ---- stage A tile(s): linear 16B/lane global loads -> XOR-swizzled ds_write_b128
  s8v B1r[4][CTW], B2r[4][CTW];
  {
    int c0 = wave * 2, c1 = c0 + 1;
    const char* g1 = (const char*)A1 + (size_t)blk * 256;
    s8v va = *(const s8v*)(g1 + c0 * 1024 + lane * 16);
    s8v vb = *(const s8v*)(g1 + c1 * 1024 + lane * 16);
    s8v vc, vd;
    if (DUAL) {
      const char* g2 = (const char*)A2 + (size_t)blk * 256;
      vc = *(const s8v*)(g2 + c0 * 1024 + lane * 16);
      vd = *(const s8v*)(g2 + c1 * 1024 + lane * 16);
    }
    // B upfront (all K) — issued while the A stage loads are in flight
#pragma unroll
    for (int kk = 0; kk < 4; ++kk)
#pragma unroll
      for (int ct = 0; ct < CTW; ++ct) {
        size_t wr = (size_t)(col0 + ct * 16 + m) * 128 + kk * 32 + quad * 8;
        B1r[kk][ct] = *(const s8v*)(W1t + wr);
        if (DUAL) B2r[kk][ct] = *(const s8v*)(W2t + wr);
      }
    int r0 = c0 * 4 + (lane >> 4);
    int r1 = r0 + 4;
    int cb = (lane & 15) << 4;
    *(s8v*)(smem + r0 * 256 + (cb ^ ((r0 & 7) << 4))) = va;
    *(s8v*)(smem + r1 * 256 + (cb ^ ((r1 & 7) << 4))) = vb;
    if (DUAL) {
      *(s8v*)(smem + 8192 + r0 * 256 + (cb ^ ((r0 & 7) << 4))) = vc;
      *(s8v*)(smem + 8192 + r1 * 256 + (cb ^ ((r1 & 7) << 4))) = vd;
    }
  }
  __syncthreads();

  // ---- K loop: A frags from LDS (swizzled, conflict-free), B from registers
  f4v acc[2][CTW];
#pragma unroll
  for (int rf = 0; rf < 2; ++rf)
#pragma unroll
    for (int ct = 0; ct < CTW; ++ct) acc[rf][ct] = (f4v){0.f, 0.f, 0.f, 0.f};
#pragma unroll
  for (int kk = 0; kk < 4; ++kk) {
    int cb2 = kk * 64 + quad * 16;
    s8v a1[2], a2[2];
#pragma unroll
    for (int rf = 0; rf < 2; ++rf) {
      int rr = rf * 16 + m;
      int sw = rr * 256 + (cb2 ^ ((rr & 7) << 4));
      a1[rf] = *(const s8v*)(smem + sw);
      if (DUAL) a2[rf] = *(const s8v*)(smem + 8192 + sw);
    }
    if (BNIN) {
      float sc[8], sh[8];
#pragma unroll
      for (int i = 0; i < 8; ++i) {
        int c = kk * 32 + quad * 8 + i;
        sc[i] = bnl[2 * c]; sh[i] = bnl[2 * c + 1];
      }
#pragma unroll
      for (int rf = 0; rf < 2; ++rf) {
        s8v raw = a1[rf];
        s8v a;
#pragma unroll
        for (int i = 0; i < 8; ++i) {
          float v = bf2f((unsigned short)raw[i]);
          v = fmaxf(v * sc[i] + sh[i], 0.0f);
          a[i] = (short)f2bf(v);
        }
        a1[rf] = a;
      }
    }
#pragma unroll
    for (int ct = 0; ct < CTW; ++ct)
#pragma unroll
      for (int rf = 0; rf < 2; ++rf) {
        acc[rf][ct] = __builtin_amdgcn_mfma_f32_16x16x32_bf16(a1[rf], B1r[kk][ct], acc[rf][ct], 0, 0, 0);
        if (DUAL)
          acc[rf][ct] = __builtin_amdgcn_mfma_f32_16x16x32_bf16(a2[rf], B2r[kk][ct], acc[rf][ct], 0, 0, 0);
      }
  }

  // ---- epilogue via LDS: bias(+relu) -> vectorized stores + stats
#pragma unroll
  for (int ct = 0; ct < CTW; ++ct) {
    int col = col0 + ct * 16 + m;
    float b = bias[col];
#pragma unroll
    for (int rf = 0; rf < 2; ++rf)
#pragma unroll
      for (int r = 0; r < 4; ++r) {
        float v = acc[rf][ct][r] + b;
        if (RELU) v = fmaxf(v, 0.0f);
        outl[(rf * 16 + quad * 4 + r) * RS + col] = v;
      }
  }
  __syncthreads();
  float s4[4] = {0.f, 0.f, 0.f, 0.f}, q4[4] = {0.f, 0.f, 0.f, 0.f};
  for (int idx = t; idx < 32 * CH; idx += 256) {
    int row = idx / CH;
    int c4 = idx % CH;      // constant per thread (256 % CH == 0)
    int gr = blk + row;
    if (gr < N) {
      f4v v = *(const f4v*)&outl[row * RS + c4 * 4];
      if (F32OUT) *(f4v*)(outF + (size_t)gr * COLS + c4 * 4) = v;
      if (BF16OUT) {
        u4v o;
#pragma unroll
        for (int j = 0; j < 4; ++j) o[j] = f2bf(v[j]);
        *(u4v*)(outB + (size_t)gr * COLS + c4 * 4) = o;
      }
      if (STATS) {
#pragma unroll
        for (int j = 0; j < 4; ++j) { s4[j] += v[j]; q4[j] += v[j] * v[j]; }
      }
    }
  }
  if (STATS) {
    __syncthreads();       // A-stage region fully dead; safe to overwrite via alias
#pragma unroll
    for (int j = 0; j < 4; ++j) { reds[t * 4 + j] = s4[j]; redq[t * 4 + j] = q4[j]; }
    __syncthreads();
    if (t < COLS) {
      int c4 = t >> 2, j = t & 3;
      float S = 0.0f, SS = 0.0f;
#pragma unroll
      for (int g = 0; g < 256 / CH; ++g) {
        S  += reds[(g * CH + c4) * 4 + j];
        SS += redq[(g * CH + c4) * 4 + j];
      }
      int slot = (blockIdx.x & 7) * COLS + t;
      atomicAdd(&sum[slot], S);
      atomicAdd(&sq[slot], SS);
    }
  }
}

// ------------- fused sage2 + MLP1: h2 = relu(mean@Wl2 + h1b@Wr2 + bl2) -> h2 fp32;
//               y1 = h2(bf16)@W1 + b1 -> y1b bf16 + 8-slot col stats.
__global__ __launch_bounds__(256, 4) void sage_mlp_kernel(
    const unsigned short* __restrict__ A1,   // mean2b
    const unsigned short* __restrict__ Wlt,
    const unsigned short* __restrict__ A2,   // h1b (self)
    const unsigned short* __restrict__ Wrt,
    const float* __restrict__ bl,
    const unsigned short* __restrict__ W1t, const float* __restrict__ b1,
    float* __restrict__ h2out, unsigned short* __restrict__ y1b,
    float* __restrict__ sum, float* __restrict__ sq, int N) {
  constexpr int RS = 132;
  constexpr int OUT_OFF = 16384;
  __shared__ char smem[OUT_OFF + 32 * RS * 4];   // 33280 B -> 4 blocks/CU
  float* outl = (float*)(smem + OUT_OFF);
  float* reds = (float*)smem;
  float* redq = (float*)(smem + 4096);
  int t = threadIdx.x;
  int wave = t >> 6, lane = t & 63;
  int quad = lane >> 4, m = lane & 15;
  int blk = blockIdx.x * 32;
  int col0 = wave * 32;

  // ---- stage A1/A2 (swizzled) + B all-K upfront
  s8v BLr[4][2], BRr[4][2];
  {
    int c0 = wave * 2, c1 = c0 + 1;
    const char* g1 = (const char*)A1 + (size_t)blk * 256;
    const char* g2 = (const char*)A2 + (size_t)blk * 256;
    s8v va = *(const s8v*)(g1 + c0 * 1024 + lane * 16);
    s8v vb = *(const s8v*)(g1 + c1 * 1024 + lane * 16);
    s8v vc = *(const s8v*)(g2 + c0 * 1024 + lane * 16);
    s8v vd = *(const s8v*)(g2 + c1 * 1024 + lane * 16);
#pragma unroll
    for (int kk = 0; kk < 4; ++kk)
#pragma unroll
      for (int ct = 0; ct < 2; ++ct) {
        size_t wr = (size_t)(col0 + ct * 16 + m) * 128 + kk * 32 + quad * 8;
        BLr[kk][ct] = *(const s8v*)(Wlt + wr);
        BRr[kk][ct] = *(const s8v*)(Wrt + wr);
      }
    int r0 = c0 * 4 + (lane >> 4);
    int r1 = r0 + 4;
    int cb = (lane & 15) << 4;
    *(s8v*)(smem + r0 * 256 + (cb ^ ((r0 & 7) << 4))) = va;
    *(s8v*)(smem + r1 * 256 + (cb ^ ((r1 & 7) << 4))) = vb;
    *(s8v*)(smem + 8192 + r0 * 256 + (cb ^ ((r0 & 7) << 4))) = vc;
    *(s8v*)(smem + 8192 + r1 * 256 + (cb ^ ((r1 & 7) << 4))) = vd;
  }
  __syncthreads();

  // ---- phase 1: dual GEMM, 32 rows x 32 cols/wave
  f4v acc[2][2];
#pragma unroll
  for (int rf = 0; rf < 2; ++rf)
#pragma unroll
    for (int ct = 0; ct < 2; ++ct) acc[rf][ct] = (f4v){0.f, 0.f, 0.f, 0.f};
#pragma unroll
  for (int kk = 0; kk < 4; ++kk) {
    int cb2 = kk * 64 + quad * 16;
    s8v a1[2], a2[2];
#pragma unroll
    for (int rf = 0; rf < 2; ++rf) {
      int rr = rf * 16 + m;
      int sw = rr * 256 + (cb2 ^ ((rr & 7) << 4));
      a1[rf] = *(const s8v*)(smem + sw);
      a2[rf] = *(const s8v*)(smem + 8192 + sw);
    }
#pragma unroll
    for (int ct = 0; ct < 2; ++ct)
#pragma unroll
      for (int rf = 0; rf < 2; ++rf) {
        acc[rf][ct] = __builtin_amdgcn_mfma_f32_16x16x32_bf16(a1[rf], BLr[kk][ct], acc[rf][ct], 0, 0, 0);
        acc[rf][ct] = __builtin_amdgcn_mfma_f32_16x16x32_bf16(a2[rf], BRr[kk][ct], acc[rf][ct], 0, 0, 0);
      }
  }

  // ---- issue ALL phase-2 W1t (own 32 cols, all K = 8 s8v) now:
  //      latency hides under epilogue + barrier + h2 store
  s8v bw[4][2];
#pragma unroll
  for (int kk = 0; kk < 4; ++kk)
#pragma unroll
    for (int ct = 0; ct < 2; ++ct)
      bw[kk][ct] = *(const s8v*)(W1t + (size_t)(col0 + ct * 16 + m) * 128 + kk * 32 + quad * 8);

  // ---- phase-1 epilogue: h2 = relu(acc + bl) -> fp32 LDS
#pragma unroll
  for (int ct = 0; ct < 2; ++ct) {
    int col = col0 + ct * 16 + m;
    float b = bl[col];
#pragma unroll
    for (int rf = 0; rf < 2; ++rf)
#pragma unroll
      for (int r = 0; r < 4; ++r)
        outl[(rf * 16 + quad * 4 + r) * RS + col] = fmaxf(acc[rf][ct][r] + b, 0.0f);
  }
  __syncthreads();

  // ---- h2 fp32 coalesced store (float4)
  for (int idx = t; idx < 32 * 32; idx += 256) {
    int row = idx >> 5;
    int c4 = idx & 31;
    int gr = blk + row;
    if (gr < N)
      *(f4v*)(h2out + (size_t)gr * 128 + c4 * 4) = *(const f4v*)&outl[row * RS + c4 * 4];
  }

  // ---- phase-2 A fragments from LDS (rows rf2*16+m), RS=132 -> ~2-way, cheap
  s8v af[2][4];
#pragma unroll
  for (int rf = 0; rf < 2; ++rf)
#pragma unroll
    for (int kk = 0; kk < 4; ++kk) {
      int k0 = kk * 32 + quad * 8;
      f4v x0 = *(const f4v*)&outl[(rf * 16 + m) * RS + k0];
      f4v x1 = *(const f4v*)&outl[(rf * 16 + m) * RS + k0 + 4];
      s8v a;
#pragma unroll
      for (int i = 0; i < 4; ++i) { a[i] = (short)f2bf(x0[i]); a[4 + i] = (short)f2bf(x1[i]); }
      af[rf][kk] = a;
    }

  // ---- phase 2: y1 = h2b @ W1 + b1 (pure-register MFMA loop)
  f4v acc2[2][2];
#pragma unroll
  for (int rf = 0; rf < 2; ++rf)
#pragma unroll
    for (int ct = 0; ct < 2; ++ct) acc2[rf][ct] = (f4v){0.f, 0.f, 0.f, 0.f};
#pragma unroll
  for (int kk = 0; kk < 4; ++kk)
#pragma unroll
    for (int ct = 0; ct < 2; ++ct)
#pragma unroll
      for (int rf = 0; rf < 2; ++rf)
        acc2[rf][ct] = __builtin_amdgcn_mfma_f32_16x16x32_bf16(af[rf][kk], bw[kk][ct], acc2[rf][ct], 0, 0, 0);
  __syncthreads();   // all outl reads (h2 store + frags) done; safe to overwrite
#pragma unroll
  for (int ct = 0; ct < 2; ++ct) {
    int col = col0 + ct * 16 + m;
    float b = b1[col];
#pragma unroll
    for (int rf = 0; rf < 2; ++rf)
#pragma unroll
      for (int r = 0; r < 4; ++r)
        outl[(rf * 16 + quad * 4 + r) * RS + col] = acc2[rf][ct][r] + b;
  }
  __syncthreads();

  // ---- y1b vectorized store (u4v) + 4-col stats (c4 = t&31 constant per thread)
  float s4[4] = {0.f, 0.f, 0.f, 0.f}, q4[4] = {0.f, 0.f, 0.f, 0.f};
  for (int idx = t; idx < 32 * 32; idx += 256) {
    int row = idx >> 5;
    int c4 = idx & 31;
    int gr = blk + row;
    if (gr < N) {
      f4v v = *(const f4v*)&outl[row * RS + c4 * 4];
      u4v o;
#pragma unroll
      for (int j = 0; j < 4; ++j) o[j] = f2bf(v[j]);
      *(u4v*)(y1b + (size_t)gr * 128 + c4 * 4) = o;
#pragma unroll
      for (int j = 0; j < 4; ++j) { s4[j] += v[j]; q4[j] += v[j] * v[j]; }
    }
  }
#pragma unroll
  for (int j = 0; j < 4; ++j) { reds[t * 4 + j] = s4[j]; redq[t * 4 + j] = q4[j]; }
  __syncthreads();
  if (t < 128) {
    int c4 = t >> 2, j = t & 3;
    float S = 0.0f, SS = 0.0f;
#pragma unroll
    for (int g = 0; g < 8; ++g) {
      S  += reds[(g * 32 + c4) * 4 + j];
      SS += redq[(g * 32 + c4) * 4 + j];
    }
    int slot = (blockIdx.x & 7) * 128 + t;
    atomicAdd(&sum[slot], S);
    atomicAdd(&sq[slot], SS);
  }
}

// ---------- fused BN(train)+ReLU (64 cols, 8 stat slots) + head dot: out = z2@W3+b3
__global__ __launch_bounds__(256) void bn_head_kernel(const float* __restrict__ y2,
    const float* __restrict__ sum, const float* __restrict__ sumsq,
    const float* __restrict__ g, const float* __restrict__ be,
    const float* __restrict__ W3, const float* __restrict__ b3,
    float* __restrict__ out, int N) {
  int wave = threadIdx.x >> 6;
  int lane = threadIdx.x & 63;
  int row = blockIdx.x * 4 + wave;
  if (row >= N) return;
  float S = 0.0f, SS = 0.0f;
#pragma unroll
  for (int k = 0; k < 8; ++k) { S += sum[k * 64 + lane]; SS += sumsq[k * 64 + lane]; }
  float invN = 1.0f / (float)N;
  float m = S * invN;
  float var = SS * invN - m * m;
  float val = (y2[(size_t)row * 64 + lane] - m) * rsqrtf(var + BN_EPS) * g[lane] + be[lane];
  val = fmaxf(val, 0.0f) * W3[lane];
#pragma unroll
  for (int off = 32; off > 0; off >>= 1) val += __shfl_down(val, off);
  if (lane == 0) out[row] = val + b3[0];
}

// ================================================================ launch
extern "C" void kernel_launch(void* const* d_in, const int* in_sizes, int n_in,
                              void* d_out, int out_size, void* d_ws, size_t ws_size,
                              hipStream_t stream) {
  const int F = 100, H = 128;
  const int N = in_sizes[0] / F;
  const int E = in_sizes[1] / 2;

  const float* x   = (const float*)d_in[0];
  const int* edge  = (const int*)d_in[1];
  const int* src   = edge;
  const int* dst   = edge + E;
  const float* Wl1 = (const float*)d_in[2];
  const float* bl1 = (const float*)d_in[3];
  const float* Wr1 = (const float*)d_in[4];
  const float* Wl2 = (const float*)d_in[5];
  const float* bl2 = (const float*)d_in[6];
  const float* Wr2 = (const float*)d_in[7];
  const float* W1  = (const float*)d_in[8];
  const float* b1  = (const float*)d_in[9];
  const float* g1  = (const float*)d_in[10];
  const float* be1 = (const float*)d_in[11];
  const float* W2  = (const float*)d_in[12];
  const float* b2  = (const float*)d_in[13];
  const float* g2  = (const float*)d_in[14];
  const float* be2 = (const float*)d_in[15];
  const float* W3  = (const float*)d_in[16];
  const float* b3  = (const float*)d_in[17];

  float* out0 = (float*)d_out;              // [N]
  float* h1   = out0 + N;                   // [N,128] fp32 (required output)
  float* h2   = h1 + (size_t)N * H;         // [N,128] fp32 (required output)

  const int NB = (N + 127) / 128;           // 391 buckets
  const int histB = (E + CHUNK - 1) / CHUNK;

  // ---- workspace layout (bucket_cnt + stat slots contiguous -> ONE small memset)
  char* wsp = (char*)d_ws;
  int* bucket_cnt = (int*)wsp;              wsp += 512 * sizeof(int);
  float* sum1    = (float*)wsp;             wsp += 8 * 128 * sizeof(float);
  float* sq1     = (float*)wsp;             wsp += 8 * 128 * sizeof(float);
  float* sum2    = (float*)wsp;             wsp += 8 * 64 * sizeof(float);
  float* sq2     = (float*)wsp;             wsp += 8 * 64 * sizeof(float);
  int* deg       = (int*)wsp;               wsp += (size_t)N * sizeof(int);
  int* row_start = (int*)wsp;               wsp += (size_t)N * sizeof(int);
  int* eidx      = (int*)wsp;               wsp += (size_t)E * sizeof(int);
  unsigned* pairs = (unsigned*)wsp;         wsp += (size_t)E * sizeof(unsigned);
  int* gcursor   = (int*)wsp;               wsp += 512 * sizeof(int);
  int* bucket_start = (int*)wsp;            wsp += 520 * sizeof(int);
  float* bufA    = (float*)wsp;             wsp += (size_t)N * 128 * sizeof(float);
  unsigned short* bfX = (unsigned short*)wsp; wsp += (size_t)N * 128 * 2; // xb
  unsigned short* bfM = (unsigned short*)wsp; wsp += (size_t)N * 128 * 2; // mean1b/mean2b
  unsigned short* bfH = (unsigned short*)wsp; wsp += (size_t)N * 128 * 2; // h1b
  unsigned short* Wl1t = (unsigned short*)wsp; wsp += 128 * 128 * 2;
  unsigned short* Wr1t = (unsigned short*)wsp; wsp += 128 * 128 * 2;
  unsigned short* Wl2t = (unsigned short*)wsp; wsp += 128 * 128 * 2;
  unsigned short* Wr2t = (unsigned short*)wsp; wsp += 128 * 128 * 2;
  unsigned short* W1t  = (unsigned short*)wsp; wsp += 128 * 128 * 2;
  unsigned short* W2t  = (unsigned short*)wsp; wsp += 64 * 128 * 2;

  unsigned short* y1b = (unsigned short*)bufA;                    // [N,128] bf16
  float* y2 = (float*)((char*)bufA + (size_t)N * 128 * 2);        // [N,64] fp32

  // ---- zero-init accumulated scratch (bucket_cnt + all stat slots, contiguous ~8KB)
  hipMemsetAsync(bucket_cnt, 0,
      512 * sizeof(int) + (8 * 128 * 2 + 8 * 64 * 2) * sizeof(float), stream);

  // ---- fused prep: bucket histogram + xcast + weight transposes (one launch)
  int xblocks = ((size_t)N * 128 + 255) / 256;
  prep_kernel<<<histB + xblocks + 352, 256, 0, stream>>>(dst, bucket_cnt, E, histB,
      x, bfX, Wl1, Wr1, Wl2, Wr2, W1, W2, Wl1t, Wr1t, Wl2t, Wr2t, W1t, W2t, N, xblocks);

  // ---- CSR build: bucket scan -> bucket scatter -> fill(+deg+row_start)
  bucket_scan_kernel<<<1, 512, 0, stream>>>(bucket_cnt, bucket_start, gcursor);
  csr_bucket_kernel<<<histB, 256, 0, stream>>>(src, dst, gcursor, pairs, E);
  csr_fill_deg_kernel<<<NB, 256, 0, stream>>>(pairs, bucket_start, eidx, row_start, deg, N);

  int gemm_grid = (N + 31) / 32;            // 1563 blocks

  // ---- layer 1: gather-mean(xb) -> bfM; sage GEMM -> h1 (fp32) + h1b (bfH)
  gather_kernel<<<(N + 3) / 4, 256, 0, stream>>>(bfX, eidx, row_start, deg, bfM, N);
  mfma_gemm_kernel<128, true, true, true, true, false, false><<<gemm_grid, 256, 0, stream>>>(
      bfM, Wl1t, bfX, Wr1t, bl1, nullptr, nullptr, nullptr, nullptr, h1, bfH, nullptr, nullptr, N);

  // ---- layer 2: gather-mean(h1b) -> bfM; fused sage2+MLP1 -> h2, y1b, stats1
  gather_kernel<<<(N + 3) / 4, 256, 0, stream>>>(bfH, eidx, row_start, deg, bfM, N);
  sage_mlp_kernel<<<gemm_grid, 256, 0, stream>>>(
      bfM, Wl2t, bfH, Wr2t, bl2, W1t, b1, h2, y1b, sum1, sq1, N);

  // ---- MLP layer 2 with fused BN1+ReLU on input (stats folded in-kernel):
  //      y2 = relu(bn(y1))@W2 + b2 + col stats
  mfma_gemm_kernel<64, false, false, true, false, true, true><<<gemm_grid, 256, 0, stream>>>(
      y1b, W2t, nullptr, nullptr, b2, sum1, sq1, g1, be1, y2, nullptr, sum2, sq2, N);

  // ---- fused BN+ReLU+head: out = relu(bn(y2)) @ W3 + b3
  bn_head_kernel<<<(N + 3) / 4, 256, 0, stream>>>(
      y2, sum2, sq2, g2, be2, W3, b3, out0, N);
}

// Round 12
// 286.110 us; speedup vs baseline: 1.0212x; 1.0212x over previous
//
#include <hip/hip_runtime.h>
#include <hip/hip_fp8.h>

#define BN_EPS 1e-5f

typedef short s8v __attribute__((ext_vector_type(8)));
typedef float f4v __attribute__((ext_vector_type(4)));
typedef unsigned short u4v __attribute__((ext_vector_type(4)));
typedef unsigned int u2v __attribute__((ext_vector_type(2)));

__device__ __forceinline__ unsigned short f2bf(float f) {
  union { float f; unsigned u; } v; v.f = f;
  unsigned r = v.u + 0x7FFF + ((v.u >> 16) & 1);
  return (unsigned short)(r >> 16);
}
__device__ __forceinline__ float bf2f(unsigned short u) {
  union { unsigned u; float f; } v; v.u = ((unsigned)u) << 16; return v.f;
}
// OCP e4m3 via HIP type (gfx950-native); encode RNE+saturate, decode HW cvt
__device__ __forceinline__ unsigned char fp8enc(float f) {
  __hip_fp8_e4m3 h(f); return (unsigned char)h.__x;
}
__device__ __forceinline__ float fp8dec(unsigned b) {
  __hip_fp8_e4m3 h; h.__x = (unsigned char)b; return (float)h;
}

#define CHUNK 4096
#define NBMAX 512

// --------- fused prep: bucket histogram (blocks [0,histB)) + xcast + 6 W transposes
// R12: xcast also writes fpX (fp8 e4m3 copy of the padded features, gather-only).
__global__ __launch_bounds__(256) void prep_kernel(
    const int* __restrict__ dst, int* __restrict__ bucket_cnt, int E, int histB,
    const float* __restrict__ x, unsigned short* __restrict__ xb,
    unsigned char* __restrict__ fpX,
    const float* __restrict__ Wl1, const float* __restrict__ Wr1,
    const float* __restrict__ Wl2, const float* __restrict__ Wr2,
    const float* __restrict__ W1, const float* __restrict__ W2,
    unsigned short* __restrict__ Wl1t, unsigned short* __restrict__ Wr1t,
    unsigned short* __restrict__ Wl2t, unsigned short* __restrict__ Wr2t,
    unsigned short* __restrict__ W1t, unsigned short* __restrict__ W2t,
    int N, int xblocks) {
  __shared__ int h[NBMAX];
  int blk = blockIdx.x;
  int t = threadIdx.x;
  if (blk < histB) {
    for (int i = t; i < NBMAX; i += 256) h[i] = 0;
    __syncthreads();
    int base = blk * CHUNK;
    int cnt = min(CHUNK, E - base);
    for (int i = t; i < cnt; i += 256) atomicAdd(&h[dst[base + i] >> 7], 1);
    __syncthreads();
    for (int i = t; i < NBMAX; i += 256)
      if (h[i] > 0) atomicAdd(&bucket_cnt[i], h[i]);
    return;
  }
  blk -= histB;
  if (blk < xblocks) {
    int tt = blk * 256 + t;
    if (tt < N * 128) {
      int col = tt & 127;
      int n = tt >> 7;
      float xv = (col < 100) ? x[n * 100 + col] : 0.0f;
      xb[tt] = f2bf(xv);
      fpX[tt] = fp8enc(xv);
    }
    return;
  }
  int w = blk - xblocks;
  const float* W; unsigned short* Wt; int K, C, base;
  if (w < 64)       { W = Wl1; Wt = Wl1t; K = 100; C = 128; base = 0;   }
  else if (w < 128) { W = Wr1; Wt = Wr1t; K = 100; C = 128; base = 64;  }
  else if (w < 192) { W = Wl2; Wt = Wl2t; K = 128; C = 128; base = 128; }
  else if (w < 256) { W = Wr2; Wt = Wr2t; K = 128; C = 128; base = 192; }
  else if (w < 320) { W = W1;  Wt = W1t;  K = 128; C = 128; base = 256; }
  else              { W = W2;  Wt = W2t;  K = 128; C = 64;  base = 320; }
  int tt = (w - base) * 256 + t;
  if (tt >= C * 128) return;
  int c = tt >> 7;
  int k = tt & 127;
  Wt[tt] = (k < K) ? f2bf(W[k * C + c]) : (unsigned short)0;
}

// ------- single 512-wide scan of bucket counts
__global__ __launch_bounds__(512) void bucket_scan_kernel(
    const int* __restrict__ bucket_cnt, int* __restrict__ bucket_start,
    int* __restrict__ gcursor) {
  __shared__ int sh[512];
  int t = threadIdx.x;
  sh[t] = bucket_cnt[t];
  __syncthreads();
  for (int d = 1; d < 512; d <<= 1) {
    int v = (t >= d) ? sh[t - d] : 0;
    __syncthreads();
    sh[t] += v;
    __syncthreads();
  }
  int excl = (t == 0) ? 0 : sh[t - 1];
  bucket_start[t] = excl;
  gcursor[t] = excl;
  if (t == 511) bucket_start[512] = sh[511];   // == E
}

// ------------------- CSR phase A: LDS-staged bucket scatter (kills partial-line writes)
__global__ __launch_bounds__(256) void csr_bucket_kernel(
    const int* __restrict__ src, const int* __restrict__ dst,
    int* __restrict__ gcursor, unsigned* __restrict__ pairs, int E) {
  __shared__ int h[NBMAX];
  __shared__ int off[NBMAX];
  __shared__ int cnt2[NBMAX];
  __shared__ int gadj[NBMAX];
  __shared__ unsigned pbuf[CHUNK];
  __shared__ unsigned short bidx[CHUNK];
  int t = threadIdx.x;
  int base = blockIdx.x * CHUNK;
  int cnt = min(CHUNK, E - base);
  for (int i = t; i < NBMAX; i += 256) { h[i] = 0; cnt2[i] = 0; }
  __syncthreads();
  for (int i = t; i < cnt; i += 256) atomicAdd(&h[dst[base + i] >> 7], 1);
  __syncthreads();
  off[t] = h[t]; off[t + 256] = h[t + 256];
  __syncthreads();
  for (int d = 1; d < 512; d <<= 1) {
    int v0 = (t >= d) ? off[t - d] : 0;
    int v1 = off[t + 256 - d];
    __syncthreads();
    off[t] += v0; off[t + 256] += v1;
    __syncthreads();
  }
  int e0 = off[t] - h[t];
  int e1 = off[t + 256] - h[t + 256];
  __syncthreads();
  off[t] = e0; off[t + 256] = e1;
  __syncthreads();
  for (int i = t; i < NBMAX; i += 256) {
    int c = h[i];
    if (c > 0) gadj[i] = atomicAdd(&gcursor[i], c) - off[i];
  }
  __syncthreads();
  for (int i = t; i < cnt; i += 256) {
    int s = src[base + i];
    int d = dst[base + i];
    int b = d >> 7;
    int p = off[b] + atomicAdd(&cnt2[b], 1);
    pbuf[p] = (unsigned)s | ((unsigned)d << 16);   // both < 2^16 (N=50000)
    bidx[p] = (unsigned short)b;
  }
  __syncthreads();
  for (int i = t; i < cnt; i += 256)
    pairs[gadj[bidx[i]] + i] = pbuf[i];
}

// ------- CSR phase B + deg: one block per bucket. Pass 1 counts the bucket's 128
// node degrees in LDS -> 128-wide scan -> row_start/deg coalesced stores.
// Pass 2 scatters eidx (pairs L2-hot).
__global__ __launch_bounds__(256) void csr_fill_deg_kernel(
    const unsigned* __restrict__ pairs, const int* __restrict__ bucket_start,
    int* __restrict__ eidx, int* __restrict__ row_start, int* __restrict__ deg,
    int N) {
  __shared__ int cnt[128];
  __shared__ int scn[128];
  __shared__ int cur[128];
  int b = blockIdx.x;
  int node0 = b << 7;
  int t = threadIdx.x;
  int pbeg = bucket_start[b];
  int pend = bucket_start[b + 1];
  if (t < 128) cnt[t] = 0;
  __syncthreads();
  for (int i = pbeg + t; i < pend; i += 256)
    atomicAdd(&cnt[(int)(pairs[i] >> 16) - node0], 1);
  __syncthreads();
  if (t < 128) scn[t] = cnt[t];
  __syncthreads();
  for (int d = 1; d < 128; d <<= 1) {
    int v = (t < 128 && t >= d) ? scn[t - d] : 0;
    __syncthreads();
    if (t < 128) scn[t] += v;
    __syncthreads();
  }
  if (t < 128) {
    int node = node0 + t;
    if (node < N) {
      int rs = pbeg + scn[t] - cnt[t];    // exclusive in-bucket prefix
      row_start[node] = rs;
      deg[node] = cnt[t];
      cur[t] = rs;
    }
  }
  __syncthreads();
  for (int i = pbeg + t; i < pend; i += 256) {
    unsigned p = pairs[i];
    int pos = atomicAdd(&cur[(int)(p >> 16) - node0], 1);
    eidx[pos] = (int)(p & 0xFFFFu);
  }
}

// ------------------ gather mean over FP8 rows (1 wave / node), R9 two-half skeleton.
// R12: features in fp8 e4m3 -> 128B/row (vs 256B bf16): halves L3 lines per row.
// 32 lanes x 4B cover a row; each lane decodes 4 fp8 -> 4 col accumulators.
// A/B vs R11 bf16: byte-proportional random-read path -> ~-45%/gather; null -> the
// path is access-proportional and the gathers are at their floor (with R9/R10).
__global__ __launch_bounds__(256) void gather_kernel(
    const unsigned char* __restrict__ feat8, const int* __restrict__ eidx,
    const int* __restrict__ row_start, const int* __restrict__ deg,
    unsigned short* __restrict__ mean_out, int N) {
  int wave = threadIdx.x >> 6;
  int lane = threadIdx.x & 63;
  int node = blockIdx.x * 4 + wave;
  if (node >= N) return;
  int beg = row_start[node];
  int d = deg[node];
  int l2 = lane & 31;
  int half = lane >> 5;
  float a0 = 0.0f, a1 = 0.0f, a2 = 0.0f, a3 = 0.0f;
  for (int i0 = 0; i0 < d; i0 += 64) {
    int cnt = min(64, d - i0);
    int my = (lane < cnt) ? eidx[beg + i0 + lane] : 0;
    int j = 0;
    for (; j + 15 < cnt; j += 16) {
      // 8 pair-loads = 16 rows in flight
      int s0 = __shfl(my, j + 0 + half);
      int s1 = __shfl(my, j + 2 + half);
      int s2 = __shfl(my, j + 4 + half);
      int s3 = __shfl(my, j + 6 + half);
      int s4 = __shfl(my, j + 8 + half);
      int s5 = __shfl(my, j + 10 + half);
      int s6 = __shfl(my, j + 12 + half);
      int s7 = __shfl(my, j + 14 + half);
      unsigned w0 = *(const unsigned*)(feat8 + (size_t)s0 * 128 + l2 * 4);
      unsigned w1 = *(const unsigned*)(feat8 + (size_t)s1 * 128 + l2 * 4);
      unsigned w2 = *(const unsigned*)(feat8 + (size_t)s2 * 128 + l2 * 4);
      unsigned w3 = *(const unsigned*)(feat8 + (size_t)s3 * 128 + l2 * 4);
      unsigned w4 = *(const unsigned*)(feat8 + (size_t)s4 * 128 + l2 * 4);
      unsigned w5 = *(const unsigned*)(feat8 + (size_t)s5 * 128 + l2 * 4);
      unsigned w6 = *(const unsigned*)(feat8 + (size_t)s6 * 128 + l2 * 4);
      unsigned w7 = *(const unsigned*)(feat8 + (size_t)s7 * 128 + l2 * 4);
      a0 += fp8dec(w0 & 255) + fp8dec(w1 & 255) + fp8dec(w2 & 255) + fp8dec(w3 & 255)
          + fp8dec(w4 & 255) + fp8dec(w5 & 255) + fp8dec(w6 & 255) + fp8dec(w7 & 255);
      a1 += fp8dec((w0 >> 8) & 255) + fp8dec((w1 >> 8) & 255) + fp8dec((w2 >> 8) & 255)
          + fp8dec((w3 >> 8) & 255) + fp8dec((w4 >> 8) & 255) + fp8dec((w5 >> 8) & 255)
          + fp8dec((w6 >> 8) & 255) + fp8dec((w7 >> 8) & 255);
      a2 += fp8dec((w0 >> 16) & 255) + fp8dec((w1 >> 16) & 255) + fp8dec((w2 >> 16) & 255)
          + fp8dec((w3 >> 16) & 255) + fp8dec((w4 >> 16) & 255) + fp8dec((w5 >> 16) & 255)
          + fp8dec((w6 >> 16) & 255) + fp8dec((w7 >> 16) & 255);
      a3 += fp8dec(w0 >> 24) + fp8dec(w1 >> 24) + fp8dec(w2 >> 24) + fp8dec(w3 >> 24)
          + fp8dec(w4 >> 24) + fp8dec(w5 >> 24) + fp8dec(w6 >> 24) + fp8dec(w7 >> 24);
    }
    for (; j < cnt; j += 2) {
      int jj = j + half;
      bool act = jj < cnt;
      int s = __shfl(my, act ? jj : 0);     // per-lane index (ds_bpermute)
      unsigned w = *(const unsigned*)(feat8 + (size_t)s * 128 + l2 * 4);
      if (act) {
        a0 += fp8dec(w & 255);
        a1 += fp8dec((w >> 8) & 255);
        a2 += fp8dec((w >> 16) & 255);
        a3 += fp8dec(w >> 24);
      }
    }
  }
  // cross-half reduce: lane L and L^32 hold the same 4 columns for different rows
  a0 += __shfl_xor(a0, 32);
  a1 += __shfl_xor(a1, 32);
  a2 += __shfl_xor(a2, 32);
  a3 += __shfl_xor(a3, 32);
  float inv = 1.0f / fmaxf((float)d, 1.0f);
  if (lane < 32) {
    u2v o;
    o[0] = (unsigned)f2bf(a0 * inv) | ((unsigned)f2bf(a1 * inv) << 16);
    o[1] = (unsigned)f2bf(a2 * inv) | ((unsigned)f2bf(a3 * inv) << 16);
    ((u2v*)(mean_out + (size_t)node * 128))[l2] = o;
  }
}

// --------------------------------------------------------- MFMA GEMM (K padded to 128)
// R10 structure (32-row blocks, LDS-staged swizzled A, all-K register B).
// BNIN folds the 8 stat slots -> scale/shift in-kernel.
// R12: optional outB8 (fp8 copy of the bf16 output, gather2-only).
template<int COLS, bool DUAL, bool RELU, bool F32OUT, bool BF16OUT, bool STATS, bool BNIN>
__global__ __launch_bounds__(256, DUAL ? 4 : 5) void mfma_gemm_kernel(
    const unsigned short* __restrict__ A1, const unsigned short* __restrict__ W1t,
    const unsigned short* __restrict__ A2, const unsigned short* __restrict__ W2t,
    const float* __restrict__ bias,
    const float* __restrict__ bsum, const float* __restrict__ bsq,
    const float* __restrict__ bg, const float* __restrict__ bbe,
    float* __restrict__ outF, unsigned short* __restrict__ outB,
    unsigned char* __restrict__ outB8,
    float* __restrict__ sum, float* __restrict__ sq, int N) {
  constexpr int CTW = COLS / 64;             // col-tiles per wave (128->2, 64->1)
  constexpr int CH = COLS / 4;               // f4 chunks per row
  constexpr int RS = COLS + 4;
  constexpr int NA = DUAL ? 2 : 1;
  constexpr int OUT_OFF = 8192 * NA;
  constexpr int BNL_OFF = OUT_OFF + 32 * RS * 4;
  constexpr int SMEM_SZ = BNL_OFF + (BNIN ? 1024 : 0);
  __shared__ char smem[SMEM_SZ];
  float* outl = (float*)(smem + OUT_OFF);
  float* reds = (float*)smem;                // alias A-stage (dead before stats write)
  float* redq = (float*)(smem + 4096);
  float* bnl  = (float*)(smem + BNL_OFF);
  int t = threadIdx.x;
  int wave = t >> 6;
  int lane = t & 63;
  int quad = lane >> 4;
  int m = lane & 15;
  int blk = blockIdx.x * 32;
  int col0 = wave * (16 * CTW);

  // ---- BNIN: fold stats -> scale/shift (covered by the stage barrier below)
  if (BNIN && t < 128) {
    float S = 0.0f, SS = 0.0f;
#pragma unroll
    for (int k = 0; k < 8; ++k) { S += bsum[k * 128 + t]; SS += bsq[k * 128 + t]; }
    float invN = 1.0f / (float)N;
    float mn = S * invN;
    float var = SS * invN - mn * mn;
    float sc = bg[t] * rsqrtf(var + BN_EPS);
    bnl[2 * t] = sc;
    bnl[2 * t + 1] = bbe[t] - mn * sc;
  }

  // ---- stage A tile(s): linear 16B/lane global loads -> XOR-swizzled ds_write_b128
  s8v B1r[4][CTW], B2r[4][CTW];
  {
    int c0 = wave * 2, c1 = c0 + 1;
    const char* g1 = (const char*)A1 + (size_t)blk * 256;
    s8v va = *(const s8v*)(g1 + c0 * 1024 + lane * 16);
    s8v vb = *(const s8v*)(g1 + c1 * 1024 + lane * 16);
    s8v vc, vd;
    if (DUAL) {
      const char* g2 = (const char*)A2 + (size_t)blk * 256;
      vc = *(const s8v*)(g2 + c0 * 1024 + lane * 16);
      vd = *(const s8v*)(g2 + c1 * 1024 + lane * 16);
    }
    // B upfront (all K) — issued while the A stage loads are in flight
#pragma unroll
    for (int kk = 0; kk < 4; ++kk)
#pragma unroll
      for (int ct = 0; ct < CTW; ++ct) {
        size_t wr = (size_t)(col0 + ct * 16 + m) * 128 + kk * 32 + quad * 8;
        B1r[kk][ct] = *(const s8v*)(W1t + wr);
        if (DUAL) B2r[kk][ct] = *(const s8v*)(W2t + wr);
      }
    int r0 = c0 * 4 + (lane >> 4);
    int r1 = r0 + 4;
    int cb = (lane & 15) << 4;
    *(s8v*)(smem + r0 * 256 + (cb ^ ((r0 & 7) << 4))) = va;
    *(s8v*)(smem + r1 * 256 + (cb ^ ((r1 & 7) << 4))) = vb;
    if (DUAL) {
      *(s8v*)(smem + 8192 + r0 * 256 + (cb ^ ((r0 & 7) << 4))) = vc;
      *(s8v*)(smem + 8192 + r1 * 256 + (cb ^ ((r1 & 7) << 4))) = vd;
    }
  }
  __syncthreads();

  // ---- K loop: A frags from LDS (swizzled, conflict-free), B from registers
  f4v acc[2][CTW];
#pragma unroll
  for (int rf = 0; rf < 2; ++rf)
#pragma unroll
    for (int ct = 0; ct < CTW; ++ct) acc[rf][ct] = (f4v){0.f, 0.f, 0.f, 0.f};
#pragma unroll
  for (int kk = 0; kk < 4; ++kk) {
    int cb2 = kk * 64 + quad * 16;
    s8v a1[2], a2[2];
#pragma unroll
    for (int rf = 0; rf < 2; ++rf) {
      int rr = rf * 16 + m;
      int sw = rr * 256 + (cb2 ^ ((rr & 7) << 4));
      a1[rf] = *(const s8v*)(smem + sw);
      if (DUAL) a2[rf] = *(const s8v*)(smem + 8192 + sw);
    }
    if (BNIN) {
      float sc[8], sh[8];
#pragma unroll
      for (int i = 0; i < 8; ++i) {
        int c = kk * 32 + quad * 8 + i;
        sc[i] = bnl[2 * c]; sh[i] = bnl[2 * c + 1];
      }
#pragma unroll
      for (int rf = 0; rf < 2; ++rf) {
        s8v raw = a1[rf];
        s8v a;
#pragma unroll
        for (int i = 0; i < 8; ++i) {
          float v = bf2f((unsigned short)raw[i]);
          v = fmaxf(v * sc[i] + sh[i], 0.0f);
          a[i] = (short)f2bf(v);
        }
        a1[rf] = a;
      }
    }
#pragma unroll
    for (int ct = 0; ct < CTW; ++ct)
#pragma unroll
      for (int rf = 0; rf < 2; ++rf) {
        acc[rf][ct] = __builtin_amdgcn_mfma_f32_16x16x32_bf16(a1[rf], B1r[kk][ct], acc[rf][ct], 0, 0, 0);
        if (DUAL)
          acc[rf][ct] = __builtin_amdgcn_mfma_f32_16x16x32_bf16(a2[rf], B2r[kk][ct], acc[rf][ct], 0, 0, 0);
      }
  }

  // ---- epilogue via LDS: bias(+relu) -> vectorized stores + stats
#pragma unroll
  for (int ct = 0; ct < CTW; ++ct) {
    int col = col0 + ct * 16 + m;
    float b = bias[col];
#pragma unroll
    for (int rf = 0; rf < 2; ++rf)
#pragma unroll
      for (int r = 0; r < 4; ++r) {
        float v = acc[rf][ct][r] + b;
        if (RELU) v = fmaxf(v, 0.0f);
        outl[(rf * 16 + quad * 4 + r) * RS + col] = v;
      }
  }
  __syncthreads();
  float s4[4] = {0.f, 0.f, 0.f, 0.f}, q4[4] = {0.f, 0.f, 0.f, 0.f};
  for (int idx = t; idx < 32 * CH; idx += 256) {
    int row = idx / CH;
    int c4 = idx % CH;      // constant per thread (256 % CH == 0)
    int gr = blk + row;
    if (gr < N) {
      f4v v = *(const f4v*)&outl[row * RS + c4 * 4];
      if (F32OUT) *(f4v*)(outF + (size_t)gr * COLS + c4 * 4) = v;
      if (BF16OUT) {
        u4v o;
#pragma unroll
        for (int j = 0; j < 4; ++j) o[j] = f2bf(v[j]);
        *(u4v*)(outB + (size_t)gr * COLS + c4 * 4) = o;
        if (outB8) {
          unsigned pk = (unsigned)fp8enc(v[0]) | ((unsigned)fp8enc(v[1]) << 8)
                      | ((unsigned)fp8enc(v[2]) << 16) | ((unsigned)fp8enc(v[3]) << 24);
          *(unsigned*)(outB8 + (size_t)gr * COLS + c4 * 4) = pk;
        }
      }
      if (STATS) {
#pragma unroll
        for (int j = 0; j < 4; ++j) { s4[j] += v[j]; q4[j] += v[j] * v[j]; }
      }
    }
  }
  if (STATS) {
    __syncthreads();       // A-stage region fully dead; safe to overwrite via alias
#pragma unroll
    for (int j = 0; j < 4; ++j) { reds[t * 4 + j] = s4[j]; redq[t * 4 + j] = q4[j]; }
    __syncthreads();
    if (t < COLS) {
      int c4 = t >> 2, j = t & 3;
      float S = 0.0f, SS = 0.0f;
#pragma unroll
      for (int g = 0; g < 256 / CH; ++g) {
        S  += reds[(g * CH + c4) * 4 + j];
        SS += redq[(g * CH + c4) * 4 + j];
      }
      int slot = (blockIdx.x & 7) * COLS + t;
      atomicAdd(&sum[slot], S);
      atomicAdd(&sq[slot], SS);
    }
  }
}

// ------------- fused sage2 + MLP1: h2 = relu(mean@Wl2 + h1b@Wr2 + bl2) -> h2 fp32;
//               y1 = h2(bf16)@W1 + b1 -> y1b bf16 + 8-slot col stats.
__global__ __launch_bounds__(256, 4) void sage_mlp_kernel(
    const unsigned short* __restrict__ A1,   // mean2b
    const unsigned short* __restrict__ Wlt,
    const unsigned short* __restrict__ A2,   // h1b (self)
    const unsigned short* __restrict__ Wrt,
    const float* __restrict__ bl,
    const unsigned short* __restrict__ W1t, const float* __restrict__ b1,
    float* __restrict__ h2out, unsigned short* __restrict__ y1b,
    float* __restrict__ sum, float* __restrict__ sq, int N) {
  constexpr int RS = 132;
  constexpr int OUT_OFF = 16384;
  __shared__ char smem[OUT_OFF + 32 * RS * 4];   // 33280 B -> 4 blocks/CU
  float* outl = (float*)(smem + OUT_OFF);
  float* reds = (float*)smem;
  float* redq = (float*)(smem + 4096);
  int t = threadIdx.x;
  int wave = t >> 6, lane = t & 63;
  int quad = lane >> 4, m = lane & 15;
  int blk = blockIdx.x * 32;
  int col0 = wave * 32;

  // ---- stage A1/A2 (swizzled) + B all-K upfront
  s8v BLr[4][2], BRr[4][2];
  {
    int c0 = wave * 2, c1 = c0 + 1;
    const char* g1 = (const char*)A1 + (size_t)blk * 256;
    const char* g2 = (const char*)A2 + (size_t)blk * 256;
    s8v va = *(const s8v*)(g1 + c0 * 1024 + lane * 16);
    s8v vb = *(const s8v*)(g1 + c1 * 1024 + lane * 16);
    s8v vc = *(const s8v*)(g2 + c0 * 1024 + lane * 16);
    s8v vd = *(const s8v*)(g2 + c1 * 1024 + lane * 16);
#pragma unroll
    for (int kk = 0; kk < 4; ++kk)
#pragma unroll
      for (int ct = 0; ct < 2; ++ct) {
        size_t wr = (size_t)(col0 + ct * 16 + m) * 128 + kk * 32 + quad * 8;
        BLr[kk][ct] = *(const s8v*)(Wlt + wr);
        BRr[kk][ct] = *(const s8v*)(Wrt + wr);
      }
    int r0 = c0 * 4 + (lane >> 4);
    int r1 = r0 + 4;
    int cb = (lane & 15) << 4;
    *(s8v*)(smem + r0 * 256 + (cb ^ ((r0 & 7) << 4))) = va;
    *(s8v*)(smem + r1 * 256 + (cb ^ ((r1 & 7) << 4))) = vb;
    *(s8v*)(smem + 8192 + r0 * 256 + (cb ^ ((r0 & 7) << 4))) = vc;
    *(s8v*)(smem + 8192 + r1 * 256 + (cb ^ ((r1 & 7) << 4))) = vd;
  }
  __syncthreads();

  // ---- phase 1: dual GEMM, 32 rows x 32 cols/wave
  f4v acc[2][2];
#pragma unroll
  for (int rf = 0; rf < 2; ++rf)
#pragma unroll
    for (int ct = 0; ct < 2; ++ct) acc[rf][ct] = (f4v){0.f, 0.f, 0.f, 0.f};
#pragma unroll
  for (int kk = 0; kk < 4; ++kk) {
    int cb2 = kk * 64 + quad * 16;
    s8v a1[2], a2[2];
#pragma unroll
    for (int rf = 0; rf < 2; ++rf) {
      int rr = rf * 16 + m;
      int sw = rr * 256 + (cb2 ^ ((rr & 7) << 4));
      a1[rf] = *(const s8v*)(smem + sw);
      a2[rf] = *(const s8v*)(smem + 8192 + sw);
    }
#pragma unroll
    for (int ct = 0; ct < 2; ++ct)
#pragma unroll
      for (int rf = 0; rf < 2; ++rf) {
        acc[rf][ct] = __builtin_amdgcn_mfma_f32_16x16x32_bf16(a1[rf], BLr[kk][ct], acc[rf][ct], 0, 0, 0);
        acc[rf][ct] = __builtin_amdgcn_mfma_f32_16x16x32_bf16(a2[rf], BRr[kk][ct], acc[rf][ct], 0, 0, 0);
      }
  }

  // ---- issue ALL phase-2 W1t (own 32 cols, all K = 8 s8v) now:
  //      latency hides under epilogue + barrier + h2 store
  s8v bw[4][2];
#pragma unroll
  for (int kk = 0; kk < 4; ++kk)
#pragma unroll
    for (int ct = 0; ct < 2; ++ct)
      bw[kk][ct] = *(const s8v*)(W1t + (size_t)(col0 + ct * 16 + m) * 128 + kk * 32 + quad * 8);

  // ---- phase-1 epilogue: h2 = relu(acc + bl) -> fp32 LDS
#pragma unroll
  for (int ct = 0; ct < 2; ++ct) {
    int col = col0 + ct * 16 + m;
    float b = bl[col];
#pragma unroll
    for (int rf = 0; rf < 2; ++rf)
#pragma unroll
      for (int r = 0; r < 4; ++r)
        outl[(rf * 16 + quad * 4 + r) * RS + col] = fmaxf(acc[rf][ct][r] + b, 0.0f);
  }
  __syncthreads();

  // ---- h2 fp32 coalesced store (float4)
  for (int idx = t; idx < 32 * 32; idx += 256) {
    int row = idx >> 5;
    int c4 = idx & 31;
    int gr = blk + row;
    if (gr < N)
      *(f4v*)(h2out + (size_t)gr * 128 + c4 * 4) = *(const f4v*)&outl[row * RS + c4 * 4];
  }

  // ---- phase-2 A fragments from LDS (rows rf2*16+m), RS=132 -> ~2-way, cheap
  s8v af[2][4];
#pragma unroll
  for (int rf = 0; rf < 2; ++rf)
#pragma unroll
    for (int kk = 0; kk < 4; ++kk) {
      int k0 = kk * 32 + quad * 8;
      f4v x0 = *(const f4v*)&outl[(rf * 16 + m) * RS + k0];
      f4v x1 = *(const f4v*)&outl[(rf * 16 + m) * RS + k0 + 4];
      s8v a;
#pragma unroll
      for (int i = 0; i < 4; ++i) { a[i] = (short)f2bf(x0[i]); a[4 + i] = (short)f2bf(x1[i]); }
      af[rf][kk] = a;
    }

  // ---- phase 2: y1 = h2b @ W1 + b1 (pure-register MFMA loop)
  f4v acc2[2][2];
#pragma unroll
  for (int rf = 0; rf < 2; ++rf)
#pragma unroll
    for (int ct = 0; ct < 2; ++ct) acc2[rf][ct] = (f4v){0.f, 0.f, 0.f, 0.f};
#pragma unroll
  for (int kk = 0; kk < 4; ++kk)
#pragma unroll
    for (int ct = 0; ct < 2; ++ct)
#pragma unroll
      for (int rf = 0; rf < 2; ++rf)
        acc2[rf][ct] = __builtin_amdgcn_mfma_f32_16x16x32_bf16(af[rf][kk], bw[kk][ct], acc2[rf][ct], 0, 0, 0);
  __syncthreads();   // all outl reads (h2 store + frags) done; safe to overwrite
#pragma unroll
  for (int ct = 0; ct < 2; ++ct) {
    int col = col0 + ct * 16 + m;
    float b = b1[col];
#pragma unroll
    for (int rf = 0; rf < 2; ++rf)
#pragma unroll
      for (int r = 0; r < 4; ++r)
        outl[(rf * 16 + quad * 4 + r) * RS + col] = acc2[rf][ct][r] + b;
  }
  __syncthreads();

  // ---- y1b vectorized store (u4v) + 4-col stats (c4 = t&31 constant per thread)
  float s4[4] = {0.f, 0.f, 0.f, 0.f}, q4[4] = {0.f, 0.f, 0.f, 0.f};
  for (int idx = t; idx < 32 * 32; idx += 256) {
    int row = idx >> 5;
    int c4 = idx & 31;
    int gr = blk + row;
    if (gr < N) {
      f4v v = *(const f4v*)&outl[row * RS + c4 * 4];
      u4v o;
#pragma unroll
      for (int j = 0; j < 4; ++j) o[j] = f2bf(v[j]);
      *(u4v*)(y1b + (size_t)gr * 128 + c4 * 4) = o;
#pragma unroll
      for (int j = 0; j < 4; ++j) { s4[j] += v[j]; q4[j] += v[j] * v[j]; }
    }
  }
#pragma unroll
  for (int j = 0; j < 4; ++j) { reds[t * 4 + j] = s4[j]; redq[t * 4 + j] = q4[j]; }
  __syncthreads();
  if (t < 128) {
    int c4 = t >> 2, j = t & 3;
    float S = 0.0f, SS = 0.0f;
#pragma unroll
    for (int g = 0; g < 8; ++g) {
      S  += reds[(g * 32 + c4) * 4 + j];
      SS += redq[(g * 32 + c4) * 4 + j];
    }
    int slot = (blockIdx.x & 7) * 128 + t;
    atomicAdd(&sum[slot], S);
    atomicAdd(&sq[slot], SS);
  }
}

// ---------- fused BN(train)+ReLU (64 cols, 8 stat slots) + head dot: out = z2@W3+b3
__global__ __launch_bounds__(256) void bn_head_kernel(const float* __restrict__ y2,
    const float* __restrict__ sum, const float* __restrict__ sumsq,
    const float* __restrict__ g, const float* __restrict__ be,
    const float* __restrict__ W3, const float* __restrict__ b3,
    float* __restrict__ out, int N) {
  int wave = threadIdx.x >> 6;
  int lane = threadIdx.x & 63;
  int row = blockIdx.x * 4 + wave;
  if (row >= N) return;
  float S = 0.0f, SS = 0.0f;
#pragma unroll
  for (int k = 0; k < 8; ++k) { S += sum[k * 64 + lane]; SS += sumsq[k * 64 + lane]; }
  float invN = 1.0f / (float)N;
  float m = S * invN;
  float var = SS * invN - m * m;
  float val = (y2[(size_t)row * 64 + lane] - m) * rsqrtf(var + BN_EPS) * g[lane] + be[lane];
  val = fmaxf(val, 0.0f) * W3[lane];
#pragma unroll
  for (int off = 32; off > 0; off >>= 1) val += __shfl_down(val, off);
  if (lane == 0) out[row] = val + b3[0];
}

// ================================================================ launch
extern "C" void kernel_launch(void* const* d_in, const int* in_sizes, int n_in,
                              void* d_out, int out_size, void* d_ws, size_t ws_size,
                              hipStream_t stream) {
  const int F = 100, H = 128;
  const int N = in_sizes[0] / F;
  const int E = in_sizes[1] / 2;

  const float* x   = (const float*)d_in[0];
  const int* edge  = (const int*)d_in[1];
  const int* src   = edge;
  const int* dst   = edge + E;
  const float* Wl1 = (const float*)d_in[2];
  const float* bl1 = (const float*)d_in[3];
  const float* Wr1 = (const float*)d_in[4];
  const float* Wl2 = (const float*)d_in[5];
  const float* bl2 = (const float*)d_in[6];
  const float* Wr2 = (const float*)d_in[7];
  const float* W1  = (const float*)d_in[8];
  const float* b1  = (const float*)d_in[9];
  const float* g1  = (const float*)d_in[10];
  const float* be1 = (const float*)d_in[11];
  const float* W2  = (const float*)d_in[12];
  const float* b2  = (const float*)d_in[13];
  const float* g2  = (const float*)d_in[14];
  const float* be2 = (const float*)d_in[15];
  const float* W3  = (const float*)d_in[16];
  const float* b3  = (const float*)d_in[17];

  float* out0 = (float*)d_out;              // [N]
  float* h1   = out0 + N;                   // [N,128] fp32 (required output)
  float* h2   = h1 + (size_t)N * H;         // [N,128] fp32 (required output)

  const int NB = (N + 127) / 128;           // 391 buckets
  const int histB = (E + CHUNK - 1) / CHUNK;

  // ---- workspace layout (bucket_cnt + stat slots contiguous -> ONE small memset)
  char* wsp = (char*)d_ws;
  int* bucket_cnt = (int*)wsp;              wsp += 512 * sizeof(int);
  float* sum1    = (float*)wsp;             wsp += 8 * 128 * sizeof(float);
  float* sq1     = (float*)wsp;             wsp += 8 * 128 * sizeof(float);
  float* sum2    = (float*)wsp;             wsp += 8 * 64 * sizeof(float);
  float* sq2     = (float*)wsp;             wsp += 8 * 64 * sizeof(float);
  int* deg       = (int*)wsp;               wsp += (size_t)N * sizeof(int);
  int* row_start = (int*)wsp;               wsp += (size_t)N * sizeof(int);
  int* eidx      = (int*)wsp;               wsp += (size_t)E * sizeof(int);
  unsigned* pairs = (unsigned*)wsp;         wsp += (size_t)E * sizeof(unsigned);
  int* gcursor   = (int*)wsp;               wsp += 512 * sizeof(int);
  int* bucket_start = (int*)wsp;            wsp += 520 * sizeof(int);
  float* bufA    = (float*)wsp;             wsp += (size_t)N * 128 * sizeof(float);
  unsigned short* bfX = (unsigned short*)wsp; wsp += (size_t)N * 128 * 2; // xb
  unsigned short* bfM = (unsigned short*)wsp; wsp += (size_t)N * 128 * 2; // mean1b/mean2b
  unsigned short* bfH = (unsigned short*)wsp; wsp += (size_t)N * 128 * 2; // h1b
  unsigned char* fpX = (unsigned char*)wsp; wsp += (size_t)N * 128;      // x fp8 (gather)
  unsigned char* fpH = (unsigned char*)wsp; wsp += (size_t)N * 128;      // h1 fp8 (gather)
  unsigned short* Wl1t = (unsigned short*)wsp; wsp += 128 * 128 * 2;
  unsigned short* Wr1t = (unsigned short*)wsp; wsp += 128 * 128 * 2;
  unsigned short* Wl2t = (unsigned short*)wsp; wsp += 128 * 128 * 2;
  unsigned short* Wr2t = (unsigned short*)wsp; wsp += 128 * 128 * 2;
  unsigned short* W1t  = (unsigned short*)wsp; wsp += 128 * 128 * 2;
  unsigned short* W2t  = (unsigned short*)wsp; wsp += 64 * 128 * 2;

  unsigned short* y1b = (unsigned short*)bufA;                    // [N,128] bf16
  float* y2 = (float*)((char*)bufA + (size_t)N * 128 * 2);        // [N,64] fp32

  // ---- zero-init accumulated scratch (bucket_cnt + all stat slots, contiguous ~8KB)
  hipMemsetAsync(bucket_cnt, 0,
      512 * sizeof(int) + (8 * 128 * 2 + 8 * 64 * 2) * sizeof(float), stream);

  // ---- fused prep: bucket histogram + xcast(bf16+fp8) + weight transposes
  int xblocks = ((size_t)N * 128 + 255) / 256;
  prep_kernel<<<histB + xblocks + 352, 256, 0, stream>>>(dst, bucket_cnt, E, histB,
      x, bfX, fpX, Wl1, Wr1, Wl2, Wr2, W1, W2, Wl1t, Wr1t, Wl2t, Wr2t, W1t, W2t, N, xblocks);

  // ---- CSR build: bucket scan -> bucket scatter -> fill(+deg+row_start)
  bucket_scan_kernel<<<1, 512, 0, stream>>>(bucket_cnt, bucket_start, gcursor);
  csr_bucket_kernel<<<histB, 256, 0, stream>>>(src, dst, gcursor, pairs, E);
  csr_fill_deg_kernel<<<NB, 256, 0, stream>>>(pairs, bucket_start, eidx, row_start, deg, N);

  int gemm_grid = (N + 31) / 32;            // 1563 blocks

  // ---- layer 1: fp8 gather-mean(fpX) -> bfM; sage GEMM -> h1 + h1b(bf16) + fpH(fp8)
  gather_kernel<<<(N + 3) / 4, 256, 0, stream>>>(fpX, eidx, row_start, deg, bfM, N);
  mfma_gemm_kernel<128, true, true, true, true, false, false><<<gemm_grid, 256, 0, stream>>>(
      bfM, Wl1t, bfX, Wr1t, bl1, nullptr, nullptr, nullptr, nullptr, h1, bfH, fpH, nullptr, nullptr, N);

  // ---- layer 2: fp8 gather-mean(fpH) -> bfM; fused sage2+MLP1 -> h2, y1b, stats1
  gather_kernel<<<(N + 3) / 4, 256, 0, stream>>>(fpH, eidx, row_start, deg, bfM, N);
  sage_mlp_kernel<<<gemm_grid, 256, 0, stream>>>(
      bfM, Wl2t, bfH, Wr2t, bl2, W1t, b1, h2, y1b, sum1, sq1, N);

  // ---- MLP layer 2 with fused BN1+ReLU on input (stats folded in-kernel):
  //      y2 = relu(bn(y1))@W2 + b2 + col stats
  mfma_gemm_kernel<64, false, false, true, false, true, true><<<gemm_grid, 256, 0, stream>>>(
      y1b, W2t, nullptr, nullptr, b2, sum1, sq1, g1, be1, y2, nullptr, nullptr, sum2, sq2, N);

  // ---- fused BN+ReLU+head: out = relu(bn(y2)) @ W3 + b3
  bn_head_kernel<<<(N + 3) / 4, 256, 0, stream>>>(
      y2, sum2, sq2, g2, be2, W3, b3, out0, N);
}